// Round 6
// baseline (54266.107 us; speedup 1.0000x reference)
//
#include <hip/hip_runtime.h>
#include <hip/hip_bf16.h>

// QLSTM (S=512,B=256,D=256,H=256,E=512), f32 in/out, bf16 MFMA internals.
// 16 persistent WGs x 1024 threads; WG i owns batch strip i (16 rows).
// ONE grid barrier per step (16 arrivals). Cross-WG data = k, vT only,
// double-buffered in ws via relaxed agent-scope (sc1) 8B atomics.
// Strip-local state: q (LDS), attn (LDS), hx (LDS), cx (registers).

typedef __hip_bfloat16 bf16;
typedef __attribute__((ext_vector_type(8))) short bf16x8;   // 8 bf16 = 4 VGPR
typedef __attribute__((ext_vector_type(4))) float f32x4;
typedef unsigned long long u64;

#define SEQ 512
#define BB  256
#define DD  256
#define HH  256
#define EE  512
#define NWG 16
#define QK_SCALE 0.04419417382415922f  // 1/sqrt(512)

// ws layout (bytes)
#define WS_K0   0          // bf16 [256][512] batch-major, step parity 0
#define WS_K1   262144     // parity 1
#define WS_VT0  524288     // bf16 [512][256] e-major, parity 0
#define WS_VT1  786432     // parity 1
#define WS_CNT  1048576    // u32 barrier counter (64B slot)
#define WS_WQ   1048640    // bf16 [512][512]
#define WS_WK   1572928    // bf16 [512][512]
#define WS_WV   2097216    // bf16 [512][512]
#define WS_WF   2621504    // bf16 [256][512]
#define WS_WI   2883648    // bf16 [256][512]
#define WS_WG   3145792    // bf16 [256][512]
#define WS_WO   3407936    // bf16 [256][512]
#define WS_END  3670080

__device__ __forceinline__ float sigm(float x) { return 1.0f / (1.0f + __expf(-x)); }

__device__ __forceinline__ unsigned short f2bf_s(float f) {
  bf16 h = __float2bfloat16(f);
  return *reinterpret_cast<unsigned short*>(&h);
}
__device__ __forceinline__ u64 pack4(float a, float b, float c, float d) {
  union { unsigned short s[4]; u64 u; } x;
  x.s[0] = f2bf_s(a); x.s[1] = f2bf_s(b); x.s[2] = f2bf_s(c); x.s[3] = f2bf_s(d);
  return x.u;
}
// relaxed agent-scope (sc1) 8B coherent load/store — no cache maintenance
__device__ __forceinline__ u64 lda8(const void* p) {
  return __hip_atomic_load((const u64*)p, __ATOMIC_RELAXED, __HIP_MEMORY_SCOPE_AGENT);
}
__device__ __forceinline__ void sta8(void* p, u64 v) {
  __hip_atomic_store((u64*)p, v, __ATOMIC_RELAXED, __HIP_MEMORY_SCOPE_AGENT);
}
__device__ __forceinline__ bf16x8 ld_frag(const bf16* p) {   // 16B = 2 coherent 8B
  union { u64 u[2]; bf16x8 v; } c;
  c.u[0] = lda8(p); c.u[1] = lda8(p + 4);
  return c.v;
}

// grid barrier: drain sc1 stores, one relaxed add + relaxed spin (16 WGs)
__device__ __forceinline__ void gbar(unsigned* cnt, unsigned target) {
  asm volatile("s_waitcnt vmcnt(0)" ::: "memory");
  __syncthreads();
  if (threadIdx.x == 0) {
    __hip_atomic_fetch_add(cnt, 1u, __ATOMIC_RELAXED, __HIP_MEMORY_SCOPE_AGENT);
    while (__hip_atomic_load(cnt, __ATOMIC_RELAXED, __HIP_MEMORY_SCOPE_AGENT) < target)
      __builtin_amdgcn_s_sleep(2);
  }
  __syncthreads();
}

// init: zero counter, convert weights f32 -> bf16 into ws
__global__ void qlstm_init_kernel(
    const float* __restrict__ Wq, const float* __restrict__ Wk, const float* __restrict__ Wv,
    const float* __restrict__ Wf, const float* __restrict__ Wi,
    const float* __restrict__ Wg, const float* __restrict__ Wo,
    char* __restrict__ wsb) {
  const int gid = blockIdx.x * blockDim.x + threadIdx.x;
  const int stride = gridDim.x * blockDim.x;
  if (gid == 0) *(unsigned*)(wsb + WS_CNT) = 0u;
  const float* srcs[7] = { Wq, Wk, Wv, Wf, Wi, Wg, Wo };
  const int offs[7] = { WS_WQ, WS_WK, WS_WV, WS_WF, WS_WI, WS_WG, WS_WO };
  const int lens[7] = { 262144, 262144, 262144, 131072, 131072, 131072, 131072 };
  for (int a = 0; a < 7; ++a) {
    bf16* dst = (bf16*)(wsb + offs[a]);
    const float* src = srcs[a];
    for (int i = gid; i < lens[a]; i += stride) dst[i] = __float2bfloat16(src[i]);
  }
}

__global__ void __launch_bounds__(1024, 1) qlstm_main_kernel(
    const float* __restrict__ x,
    const float* __restrict__ bfv, const float* __restrict__ biv,
    const float* __restrict__ bgv, const float* __restrict__ bov,
    float* __restrict__ out, char* __restrict__ wsb)
{
  bf16* k_buf[2]  = { (bf16*)(wsb + WS_K0),  (bf16*)(wsb + WS_K1)  };
  bf16* vT_buf[2] = { (bf16*)(wsb + WS_VT0), (bf16*)(wsb + WS_VT1) };
  const bf16* wq_b = (const bf16*)(wsb + WS_WQ);
  const bf16* wk_b = (const bf16*)(wsb + WS_WK);
  const bf16* wv_b = (const bf16*)(wsb + WS_WV);
  const bf16* wf_b = (const bf16*)(wsb + WS_WF);
  const bf16* wi_b = (const bf16*)(wsb + WS_WI);
  const bf16* wg_b = (const bf16*)(wsb + WS_WG);
  const bf16* wo_b = (const bf16*)(wsb + WS_WO);
  unsigned* cnt = (unsigned*)(wsb + WS_CNT);

  const int sb   = blockIdx.x;   // strip 0..15 (batch rows sb*16..sb*16+15)
  const int tid  = threadIdx.x;
  const int wid  = tid >> 6;     // wave 0..15
  const int lane = tid & 63;
  const int l16  = lane & 15;
  const int kq   = lane >> 4;    // 0..3
  const int r0   = sb * 16;

  __shared__ unsigned short cstage[16 * 520];   // A: comb [x|hx]; D/E: attn strip
  __shared__ unsigned short q_lds[16 * 520];    // q strip, batch-major (pad 8)
  __shared__ float          s_lds[16 * 256];    // scores f32 / h repack
  __shared__ unsigned short p_lds[16 * 264];    // softmax probs bf16 (+8 pad/row)
  __shared__ unsigned short hx_lds[16 * 256];   // strip hx, bf16

  // zero strip hx (4096 elems, 1024 threads x 4)
  *(u64*)&hx_lds[tid * 4] = 0ull;
  __syncthreads();

  f32x4 cxr = {0.f, 0.f, 0.f, 0.f};   // lane-private cell state (16x16 per wave)

  for (int t = 0; t < SEQ; ++t) {
    const int par = t & 1;
    bf16* kb  = k_buf[par];
    bf16* vtb = vT_buf[par];

    // ============ Phase A: stage comb, compute q(local), k,vT(publish) ======
    {
      const int row = tid >> 6, off = (tid & 63) * 4;
      const float4 xf = *(const float4*)(x + ((size_t)t * BB + r0 + row) * DD + off);
      *(u64*)(&cstage[row * 520 + off]) = pack4(xf.x, xf.y, xf.z, xf.w);
      *(u64*)(&cstage[row * 520 + 256 + off]) = *(const u64*)(&hx_lds[row * 256 + off]);
    }
    __syncthreads();
    #pragma unroll
    for (int s6 = 0; s6 < 6; ++s6) {
      const int T = wid * 6 + s6;               // 0..95
      const unsigned short* crow = &cstage[l16 * 520];
      if (T < 32) {
        // q (swapped: A=Wq rows n, B=comb rows batch) -> q_lds[batch][n] contig
        const int n0 = T * 16;
        const bf16* wrow = wq_b + (size_t)(n0 + l16) * EE;
        f32x4 acc = {0.f, 0.f, 0.f, 0.f};
        #pragma unroll
        for (int ks = 0; ks < 16; ++ks) {
          const int kg = ks * 32 + kq * 8;
          bf16x8 wf = *(const bf16x8*)(wrow + kg);
          bf16x8 cf = *(const bf16x8*)(crow + kg);
          acc = __builtin_amdgcn_mfma_f32_16x16x32_bf16(wf, cf, acc, 0, 0, 0);
        }
        *(u64*)(&q_lds[l16 * 520 + n0 + kq * 4]) = pack4(acc[0], acc[1], acc[2], acc[3]);
      } else if (T < 64) {
        // k (swapped) -> k_buf[batch][e] row-contig, sc1
        const int n0 = (T - 32) * 16;
        const bf16* wrow = wk_b + (size_t)(n0 + l16) * EE;
        f32x4 acc = {0.f, 0.f, 0.f, 0.f};
        #pragma unroll
        for (int ks = 0; ks < 16; ++ks) {
          const int kg = ks * 32 + kq * 8;
          bf16x8 wf = *(const bf16x8*)(wrow + kg);
          bf16x8 cf = *(const bf16x8*)(crow + kg);
          acc = __builtin_amdgcn_mfma_f32_16x16x32_bf16(wf, cf, acc, 0, 0, 0);
        }
        sta8(kb + (size_t)(r0 + l16) * EE + n0 + kq * 4,
             pack4(acc[0], acc[1], acc[2], acc[3]));
      } else {
        // v (normal: A=comb rows batch, B=Wv rows n) -> vT[n][batch] contig, sc1
        const int n0 = (T - 64) * 16;
        const bf16* wrow = wv_b + (size_t)(n0 + l16) * EE;
        f32x4 acc = {0.f, 0.f, 0.f, 0.f};
        #pragma unroll
        for (int ks = 0; ks < 16; ++ks) {
          const int kg = ks * 32 + kq * 8;
          bf16x8 cf = *(const bf16x8*)(crow + kg);
          bf16x8 wf = *(const bf16x8*)(wrow + kg);
          acc = __builtin_amdgcn_mfma_f32_16x16x32_bf16(cf, wf, acc, 0, 0, 0);
        }
        sta8(vtb + (size_t)(n0 + l16) * BB + r0 + kq * 4,
             pack4(acc[0], acc[1], acc[2], acc[3]));
      }
    }
    gbar(cnt, (unsigned)(t + 1) * NWG);

    // ============ B: scores strip 16x256 (wave wid -> cols wid*16..) =========
    {
      const int j0 = wid * 16;
      const unsigned short* qrow = &q_lds[l16 * 520];
      const bf16* krow = kb + (size_t)(j0 + l16) * EE;
      f32x4 acc = {0.f, 0.f, 0.f, 0.f};
      #pragma unroll
      for (int ks = 0; ks < 16; ++ks) {
        const int kg = ks * 32 + kq * 8;
        bf16x8 a = *(const bf16x8*)(qrow + kg);
        bf16x8 b = ld_frag(krow + kg);
        acc = __builtin_amdgcn_mfma_f32_16x16x32_bf16(a, b, acc, 0, 0, 0);
      }
      #pragma unroll
      for (int r = 0; r < 4; ++r)
        s_lds[(kq * 4 + r) * 256 + j0 + l16] = acc[r];
    }
    __syncthreads();
    // ============ C: softmax row i = wid =====================================
    {
      const int i = wid;
      const float4 v = *(const float4*)(&s_lds[i * 256 + lane * 4]);
      float m = fmaxf(fmaxf(v.x, v.y), fmaxf(v.z, v.w));
      #pragma unroll
      for (int off = 32; off > 0; off >>= 1) m = fmaxf(m, __shfl_xor(m, off));
      float e0 = __expf((v.x - m) * QK_SCALE);
      float e1 = __expf((v.y - m) * QK_SCALE);
      float e2 = __expf((v.z - m) * QK_SCALE);
      float e3 = __expf((v.w - m) * QK_SCALE);
      float s = e0 + e1 + e2 + e3;
      #pragma unroll
      for (int off = 32; off > 0; off >>= 1) s += __shfl_xor(s, off);
      const float rinv = 1.0f / s;
      unsigned short* pp = &p_lds[i * 264 + lane * 4];
      pp[0] = f2bf_s(e0 * rinv);
      pp[1] = f2bf_s(e1 * rinv);
      pp[2] = f2bf_s(e2 * rinv);
      pp[3] = f2bf_s(e3 * rinv);
    }
    __syncthreads();
    // ============ D: attn strip -> cstage (swapped: A=vT rows n, B=P rows) ===
    #pragma unroll
    for (int q8 = 0; q8 < 2; ++q8) {
      const int n0 = wid * 16 + q8 * 256;
      const bf16* vrow = vtb + (size_t)(n0 + l16) * BB;
      const unsigned short* prow = &p_lds[l16 * 264];
      f32x4 acc = {0.f, 0.f, 0.f, 0.f};
      #pragma unroll
      for (int ks = 0; ks < 8; ++ks) {
        const int kg = ks * 32 + kq * 8;
        bf16x8 vf = ld_frag(vrow + kg);
        bf16x8 pf = *(const bf16x8*)(prow + kg);
        acc = __builtin_amdgcn_mfma_f32_16x16x32_bf16(vf, pf, acc, 0, 0, 0);
      }
      *(u64*)(&cstage[l16 * 520 + n0 + kq * 4]) = pack4(acc[0], acc[1], acc[2], acc[3]);
    }
    __syncthreads();
    // ============ E: gates (wave wid -> hcols wid*16..) + LSTM in regs =======
    {
      const unsigned short* arow = &cstage[l16 * 520];
      const bf16* wfr = wf_b + (size_t)(wid * 16 + l16) * EE;
      const bf16* wir = wi_b + (size_t)(wid * 16 + l16) * EE;
      const bf16* wgr = wg_b + (size_t)(wid * 16 + l16) * EE;
      const bf16* wor = wo_b + (size_t)(wid * 16 + l16) * EE;
      f32x4 aF = {0.f,0.f,0.f,0.f}, aI = {0.f,0.f,0.f,0.f};
      f32x4 aG = {0.f,0.f,0.f,0.f}, aO = {0.f,0.f,0.f,0.f};
      #pragma unroll
      for (int ks = 0; ks < 16; ++ks) {
        const int kg = ks * 32 + kq * 8;
        bf16x8 af = *(const bf16x8*)(arow + kg);
        aF = __builtin_amdgcn_mfma_f32_16x16x32_bf16(af, *(const bf16x8*)(wfr + kg), aF, 0, 0, 0);
        aI = __builtin_amdgcn_mfma_f32_16x16x32_bf16(af, *(const bf16x8*)(wir + kg), aI, 0, 0, 0);
        aG = __builtin_amdgcn_mfma_f32_16x16x32_bf16(af, *(const bf16x8*)(wgr + kg), aG, 0, 0, 0);
        aO = __builtin_amdgcn_mfma_f32_16x16x32_bf16(af, *(const bf16x8*)(wor + kg), aO, 0, 0, 0);
      }
      const int col = wid * 16 + l16;
      const float bfc = bfv[col], bic = biv[col], bgc = bgv[col], boc = bov[col];
      float h4[4], c4v[4];
      #pragma unroll
      for (int r = 0; r < 4; ++r) {
        const float F = sigm(aF[r] + bfc);
        const float I = sigm(aI[r] + bic);
        const float G = tanhf(aG[r] + bgc);
        const float O = sigm(aO[r] + boc);
        const float c2 = F * cxr[r] + I * G;
        cxr[r] = c2;
        c4v[r] = c2;
        h4[r]  = O * tanhf(c2);
      }
      #pragma unroll
      for (int r = 0; r < 4; ++r)
        s_lds[wid * 256 + (kq * 4 + r) * 16 + l16] = h4[r];
      if (t == SEQ - 1) {
        #pragma unroll
        for (int r = 0; r < 4; ++r)
          out[(size_t)SEQ * 65536 + 65536 + (size_t)(r0 + kq * 4 + r) * 256 + col] = c4v[r];
      }
    }
    __syncthreads();
    // ============ repack h: hx_lds (bf16) + out (f32, row-contiguous) ========
    {
      const int row = tid >> 6, c4 = (tid & 63) * 4;
      float hv[4];
      #pragma unroll
      for (int e = 0; e < 4; ++e)
        hv[e] = s_lds[((c4 + e) >> 4) * 256 + row * 16 + ((c4 + e) & 15)];
      *(u64*)(&hx_lds[row * 256 + c4]) = pack4(hv[0], hv[1], hv[2], hv[3]);
      *(float4*)(out + (size_t)t * 65536 + (size_t)(r0 + row) * 256 + c4) =
          make_float4(hv[0], hv[1], hv[2], hv[3]);
      if (t == SEQ - 1)
        *(float4*)(out + (size_t)SEQ * 65536 + (size_t)(r0 + row) * 256 + c4) =
            make_float4(hv[0], hv[1], hv[2], hv[3]);
    }
    __syncthreads();   // hx_lds/s_lds/cstage stable before next iteration
  }
}

extern "C" void kernel_launch(void* const* d_in, const int* in_sizes, int n_in,
                              void* d_out, int out_size, void* d_ws, size_t ws_size,
                              hipStream_t stream) {
  const float* x   = (const float*)d_in[0];
  const float* Wq  = (const float*)d_in[1];
  const float* Wk  = (const float*)d_in[2];
  const float* Wv  = (const float*)d_in[3];
  const float* Wf  = (const float*)d_in[4];
  const float* bfv = (const float*)d_in[5];
  const float* Wi  = (const float*)d_in[6];
  const float* biv = (const float*)d_in[7];
  const float* Wgg = (const float*)d_in[8];
  const float* bgv = (const float*)d_in[9];
  const float* Wo  = (const float*)d_in[10];
  const float* bov = (const float*)d_in[11];
  float* out = (float*)d_out;
  char* wsb = (char*)d_ws;

  hipLaunchKernelGGL(qlstm_init_kernel, dim3(512), dim3(256), 0, stream,
                     Wq, Wk, Wv, Wf, Wi, Wgg, Wo, wsb);

  void* args[] = { (void*)&x, (void*)&bfv, (void*)&biv, (void*)&bgv, (void*)&bov,
                   (void*)&out, (void*)&wsb };
  hipLaunchCooperativeKernel((void*)qlstm_main_kernel, dim3(NWG), dim3(1024),
                             args, 0, stream);
}

// Round 7
// 41063.202 us; speedup vs baseline: 1.3215x; 1.3215x over previous
//
#include <hip/hip_runtime.h>
#include <hip/hip_bf16.h>

// QLSTM (S=512,B=256,D=256,H=256,E=512), f32 in/out, bf16 MFMA internals.
// 256 persistent WGs x 1024 threads; 2 grid barriers per step.
//   A    : q,k,vT = [x_t|hx] @ [Wq|Wk|Wv]^T   (all WGs, 6 tiles each)
//   BCDE : scores->softmax->attn->gates->LSTM  (strip WGs wg<16)
// Cross-WG data via relaxed agent-scope (sc1) 8B atomics.
// Barrier: per-WG arrival flags (distinct lines) + aggregator WG255 +
// 8 replicated release lines (read-only polling) — no RMW/poll contention.

typedef __hip_bfloat16 bf16;
typedef __attribute__((ext_vector_type(8))) short bf16x8;   // 8 bf16 = 4 VGPR
typedef __attribute__((ext_vector_type(4))) float f32x4;
typedef unsigned long long u64;

#define SEQ 512
#define BB  256
#define DD  256
#define HH  256
#define EE  512
#define NWG 256
#define QK_SCALE 0.04419417382415922f  // 1/sqrt(512)

// ws layout (bytes)
#define WS_Q     0          // bf16 [256][512]  batch-major
#define WS_K     262144     // bf16 [256][512]  batch-major
#define WS_VT    524288     // bf16 [512][256]  e-major (v transposed)
#define WS_HX    1048576    // bf16 [256][256]  batch-major
#define WS_CX    1179648    // f32  lane-private layout, 256KB
#define WS_WQ    1441792    // bf16 [512][512]
#define WS_WK    1966080    // bf16 [512][512]
#define WS_WV    2490368    // bf16 [512][512]
#define WS_WF    3014656    // bf16 [256][512]
#define WS_WI    3276800    // bf16 [256][512]
#define WS_WG    3538944    // bf16 [256][512]
#define WS_WO    3801088    // bf16 [256][512]
#define WS_FLAGS 4063232    // u32 [256] stride 64B  (arrival flags)
#define WS_REL   4079616    // u32 [8]   stride 64B  (release copies)
#define WS_END   4080128

__device__ __forceinline__ float sigm(float x) { return 1.0f / (1.0f + __expf(-x)); }

__device__ __forceinline__ unsigned short f2bf_s(float f) {
  bf16 h = __float2bfloat16(f);
  return *reinterpret_cast<unsigned short*>(&h);
}
__device__ __forceinline__ u64 pack4(float a, float b, float c, float d) {
  union { unsigned short s[4]; u64 u; } x;
  x.s[0] = f2bf_s(a); x.s[1] = f2bf_s(b); x.s[2] = f2bf_s(c); x.s[3] = f2bf_s(d);
  return x.u;
}
// relaxed agent-scope (sc1) coherent ops — no cache-maintenance fences
__device__ __forceinline__ u64 lda8(const void* p) {
  return __hip_atomic_load((const u64*)p, __ATOMIC_RELAXED, __HIP_MEMORY_SCOPE_AGENT);
}
__device__ __forceinline__ void sta8(void* p, u64 v) {
  __hip_atomic_store((u64*)p, v, __ATOMIC_RELAXED, __HIP_MEMORY_SCOPE_AGENT);
}
__device__ __forceinline__ unsigned lda4(const unsigned* p) {
  return __hip_atomic_load(p, __ATOMIC_RELAXED, __HIP_MEMORY_SCOPE_AGENT);
}
__device__ __forceinline__ void sta4(unsigned* p, unsigned v) {
  __hip_atomic_store(p, v, __ATOMIC_RELAXED, __HIP_MEMORY_SCOPE_AGENT);
}
__device__ __forceinline__ bf16x8 ld_frag(const bf16* p) {   // 16B = 2 coherent 8B
  union { u64 u[2]; bf16x8 v; } c;
  c.u[0] = lda8(p); c.u[1] = lda8(p + 4);
  return c.v;
}
__device__ __forceinline__ void st8(bf16* p, f32x4 v) {
  sta8(p, pack4(v[0], v[1], v[2], v[3]));
}

// flag-tree grid barrier (monotonic val; aggregator = WG NWG-1)
__device__ __forceinline__ void gbar(unsigned* flags, unsigned* rel,
                                     int wg, unsigned val) {
  asm volatile("s_waitcnt vmcnt(0)" ::: "memory");  // drain sc1 data stores
  __syncthreads();
  const int tid = threadIdx.x;
  if (wg == NWG - 1) {
    if (tid < 64) {
      if (tid == 0) sta4(&flags[(NWG - 1) * 16], val);
      for (;;) {                       // scan 256 flags, 4 per lane
        bool ok = true;
        #pragma unroll
        for (int j = 0; j < 4; ++j)
          ok &= (lda4(&flags[(tid * 4 + j) * 16]) >= val);
        if (__ballot(ok) == ~0ull) break;
        __builtin_amdgcn_s_sleep(4);
      }
      if (tid < 8) sta4(&rel[tid * 16], val);   // replicate release
    }
  } else {
    if (tid == 0) {
      sta4(&flags[wg * 16], val);
      while (lda4(&rel[(wg & 7) * 16]) < val)
        __builtin_amdgcn_s_sleep(8);
    }
  }
  __syncthreads();
}

// init: zero hx/cx/flags/release, convert weights f32 -> bf16 into ws
__global__ void qlstm_init_kernel(
    const float* __restrict__ Wq, const float* __restrict__ Wk, const float* __restrict__ Wv,
    const float* __restrict__ Wf, const float* __restrict__ Wi,
    const float* __restrict__ Wg, const float* __restrict__ Wo,
    char* __restrict__ wsb) {
  const int gid = blockIdx.x * blockDim.x + threadIdx.x;
  const int stride = gridDim.x * blockDim.x;
  bf16*  hx = (bf16*)(wsb + WS_HX);
  float* cx = (float*)(wsb + WS_CX);
  unsigned* sync = (unsigned*)(wsb + WS_FLAGS);
  for (int i = gid; i < (WS_END - WS_FLAGS) / 4; i += stride) sync[i] = 0u;
  for (int i = gid; i < 65536; i += stride) { hx[i] = __float2bfloat16(0.0f); cx[i] = 0.0f; }
  const float* srcs[7] = { Wq, Wk, Wv, Wf, Wi, Wg, Wo };
  const int offs[7] = { WS_WQ, WS_WK, WS_WV, WS_WF, WS_WI, WS_WG, WS_WO };
  const int lens[7] = { 262144, 262144, 262144, 131072, 131072, 131072, 131072 };
  for (int a = 0; a < 7; ++a) {
    bf16* dst = (bf16*)(wsb + offs[a]);
    const float* src = srcs[a];
    for (int i = gid; i < lens[a]; i += stride) dst[i] = __float2bfloat16(src[i]);
  }
}

__global__ void __launch_bounds__(1024, 1) qlstm_main_kernel(
    const float* __restrict__ x,
    const float* __restrict__ bfv, const float* __restrict__ biv,
    const float* __restrict__ bgv, const float* __restrict__ bov,
    float* __restrict__ out, char* __restrict__ wsb)
{
  bf16*  q_ws  = (bf16*)(wsb + WS_Q);
  bf16*  k_ws  = (bf16*)(wsb + WS_K);
  bf16*  vT_ws = (bf16*)(wsb + WS_VT);
  bf16*  hx_ws = (bf16*)(wsb + WS_HX);
  float* cx_ws = (float*)(wsb + WS_CX);
  const bf16* wq_b = (const bf16*)(wsb + WS_WQ);
  const bf16* wk_b = (const bf16*)(wsb + WS_WK);
  const bf16* wv_b = (const bf16*)(wsb + WS_WV);
  const bf16* wf_b = (const bf16*)(wsb + WS_WF);
  const bf16* wi_b = (const bf16*)(wsb + WS_WI);
  const bf16* wg_b = (const bf16*)(wsb + WS_WG);
  const bf16* wo_b = (const bf16*)(wsb + WS_WO);
  unsigned* flags = (unsigned*)(wsb + WS_FLAGS);
  unsigned* rel   = (unsigned*)(wsb + WS_REL);

  const int wg   = blockIdx.x;
  const int tid  = threadIdx.x;
  const int wid  = tid >> 6;     // wave 0..15
  const int lane = tid & 63;
  const int l16  = lane & 15;
  const int kq   = lane >> 4;    // 0..3

  __shared__ unsigned short cstage[16 * 520];   // A: comb [x|hx]; D/E: attn strip
  __shared__ float          s_lds[16 * 256];    // scores f32 / h repack
  __shared__ unsigned short p_lds[16 * 264];    // softmax probs bf16 (+8 pad/row)

  const int rb = wg >> 4;        // batch row-block this WG stages in phase A

  unsigned bexp = 0;

  for (int t = 0; t < SEQ; ++t) {
    // ============ Phase A: q,k,vT  (all WGs; 6 tiles each) ============
    {
      const int row = tid >> 6, off = (tid & 63) * 4;
      const float4 xf = *(const float4*)(x + ((size_t)t * BB + rb * 16 + row) * DD + off);
      *(u64*)(&cstage[row * 520 + off]) = pack4(xf.x, xf.y, xf.z, xf.w);
      *(u64*)(&cstage[row * 520 + 256 + off]) = lda8(hx_ws + (rb * 16 + row) * HH + off);
    }
    __syncthreads();
    if (wid < 6) {
      const int cb = (wg & 15) * 6 + wid;       // 0..95
      const unsigned short* crow = &cstage[l16 * 520];
      if (cb < 64) {
        // q,k: SWAPPED operands -> rows = out-col n, cols = batch
        const bf16* W = (cb < 32) ? wq_b : wk_b;
        const int n0 = (cb & 31) * 16;
        const bf16* wrow = W + (size_t)(n0 + l16) * EE;
        f32x4 acc = {0.f, 0.f, 0.f, 0.f};
        #pragma unroll
        for (int ks = 0; ks < 16; ++ks) {
          const int kg = ks * 32 + kq * 8;
          bf16x8 wf = *(const bf16x8*)(wrow + kg);
          bf16x8 cf = *(const bf16x8*)(crow + kg);
          acc = __builtin_amdgcn_mfma_f32_16x16x32_bf16(wf, cf, acc, 0, 0, 0);
        }
        bf16* dst = (cb < 32) ? q_ws : k_ws;
        st8(dst + (size_t)(rb * 16 + l16) * EE + n0 + kq * 4, acc);
      } else {
        // v: normal order -> rows = batch, cols = e  => vT row-contig
        const int n0 = (cb - 64) * 16;
        const bf16* wrow = wv_b + (size_t)(n0 + l16) * EE;
        f32x4 acc = {0.f, 0.f, 0.f, 0.f};
        #pragma unroll
        for (int ks = 0; ks < 16; ++ks) {
          const int kg = ks * 32 + kq * 8;
          bf16x8 cf = *(const bf16x8*)(crow + kg);
          bf16x8 wf = *(const bf16x8*)(wrow + kg);
          acc = __builtin_amdgcn_mfma_f32_16x16x32_bf16(cf, wf, acc, 0, 0, 0);
        }
        st8(vT_ws + (size_t)(n0 + l16) * BB + rb * 16 + kq * 4, acc);
      }
    }
    gbar(flags, rel, wg, ++bexp);

    // ============ Phase BCDE: strip WGs (wg<16) do scores..LSTM ============
    if (wg < 16) {
      const int r0 = wg * 16;
      // ---- B: scores tile (strip rows x cols j0..j0+16), K=512
      {
        const int j0 = wid * 16;
        const bf16* qrow = q_ws + (size_t)(r0 + l16) * EE;
        const bf16* krow = k_ws + (size_t)(j0 + l16) * EE;
        f32x4 acc = {0.f, 0.f, 0.f, 0.f};
        #pragma unroll
        for (int ks = 0; ks < 16; ++ks) {
          const int kg = ks * 32 + kq * 8;
          bf16x8 a = ld_frag(qrow + kg);
          bf16x8 b = ld_frag(krow + kg);
          acc = __builtin_amdgcn_mfma_f32_16x16x32_bf16(a, b, acc, 0, 0, 0);
        }
        #pragma unroll
        for (int r = 0; r < 4; ++r)
          s_lds[(kq * 4 + r) * 256 + j0 + l16] = acc[r];
      }
      __syncthreads();
      // ---- C: softmax row i = wid
      {
        const int i = wid;
        const float4 v = *(const float4*)(&s_lds[i * 256 + lane * 4]);
        float m = fmaxf(fmaxf(v.x, v.y), fmaxf(v.z, v.w));
        #pragma unroll
        for (int off = 32; off > 0; off >>= 1) m = fmaxf(m, __shfl_xor(m, off));
        float e0 = __expf((v.x - m) * QK_SCALE);
        float e1 = __expf((v.y - m) * QK_SCALE);
        float e2 = __expf((v.z - m) * QK_SCALE);
        float e3 = __expf((v.w - m) * QK_SCALE);
        float s = e0 + e1 + e2 + e3;
        #pragma unroll
        for (int off = 32; off > 0; off >>= 1) s += __shfl_xor(s, off);
        const float rinv = 1.0f / s;
        unsigned short* pp = &p_lds[i * 264 + lane * 4];
        pp[0] = f2bf_s(e0 * rinv);
        pp[1] = f2bf_s(e1 * rinv);
        pp[2] = f2bf_s(e2 * rinv);
        pp[3] = f2bf_s(e3 * rinv);
      }
      __syncthreads();
      // ---- D: attn strip -> cstage (swapped: A=vT rows n, B=P rows i)
      #pragma unroll
      for (int q8 = 0; q8 < 2; ++q8) {
        const int n0 = wid * 16 + q8 * 256;
        const bf16* vrow = vT_ws + (size_t)(n0 + l16) * BB;
        const unsigned short* prow = &p_lds[l16 * 264];
        f32x4 acc = {0.f, 0.f, 0.f, 0.f};
        #pragma unroll
        for (int ks = 0; ks < 8; ++ks) {
          const int kg = ks * 32 + kq * 8;
          bf16x8 vf = ld_frag(vrow + kg);
          bf16x8 pf = *(const bf16x8*)(prow + kg);
          acc = __builtin_amdgcn_mfma_f32_16x16x32_bf16(vf, pf, acc, 0, 0, 0);
        }
        *(u64*)(&cstage[l16 * 520 + n0 + kq * 4]) = pack4(acc[0], acc[1], acc[2], acc[3]);
      }
      __syncthreads();
      // ---- E: gates (wave wid owns hcol block wid*16) + LSTM update in regs
      {
        const unsigned short* arow = &cstage[l16 * 520];
        const bf16* wfr = wf_b + (size_t)(wid * 16 + l16) * EE;
        const bf16* wir = wi_b + (size_t)(wid * 16 + l16) * EE;
        const bf16* wgr = wg_b + (size_t)(wid * 16 + l16) * EE;
        const bf16* wor = wo_b + (size_t)(wid * 16 + l16) * EE;
        f32x4 aF = {0.f,0.f,0.f,0.f}, aI = {0.f,0.f,0.f,0.f};
        f32x4 aG = {0.f,0.f,0.f,0.f}, aO = {0.f,0.f,0.f,0.f};
        #pragma unroll
        for (int ks = 0; ks < 16; ++ks) {
          const int kg = ks * 32 + kq * 8;
          bf16x8 af = *(const bf16x8*)(arow + kg);
          aF = __builtin_amdgcn_mfma_f32_16x16x32_bf16(af, *(const bf16x8*)(wfr + kg), aF, 0, 0, 0);
          aI = __builtin_amdgcn_mfma_f32_16x16x32_bf16(af, *(const bf16x8*)(wir + kg), aI, 0, 0, 0);
          aG = __builtin_amdgcn_mfma_f32_16x16x32_bf16(af, *(const bf16x8*)(wgr + kg), aG, 0, 0, 0);
          aO = __builtin_amdgcn_mfma_f32_16x16x32_bf16(af, *(const bf16x8*)(wor + kg), aO, 0, 0, 0);
        }
        const int col = wid * 16 + l16;
        const float bfc = bfv[col], bic = biv[col], bgc = bgv[col], boc = bov[col];
        float* cxp = cx_ws + ((size_t)(wg * 16 + wid) * 64 + lane) * 4;  // lane-private
        const float4 cxv = *(const float4*)cxp;
        const float cxa[4] = { cxv.x, cxv.y, cxv.z, cxv.w };
        float h4[4], c4v[4];
        #pragma unroll
        for (int r = 0; r < 4; ++r) {
          const float F = sigm(aF[r] + bfc);
          const float I = sigm(aI[r] + bic);
          const float G = tanhf(aG[r] + bgc);
          const float O = sigm(aO[r] + boc);
          const float c2 = F * cxa[r] + I * G;
          c4v[r] = c2;
          h4[r]  = O * tanhf(c2);
        }
        *(float4*)cxp = make_float4(c4v[0], c4v[1], c4v[2], c4v[3]);
        #pragma unroll
        for (int r = 0; r < 4; ++r)
          s_lds[wid * 256 + (kq * 4 + r) * 16 + l16] = h4[r];
        if (t == SEQ - 1) {
          #pragma unroll
          for (int r = 0; r < 4; ++r)
            out[(size_t)SEQ * 65536 + 65536 + (size_t)(r0 + kq * 4 + r) * 256 + col] = c4v[r];
        }
      }
      __syncthreads();
      // ---- repack h: coherent hx store + f32 out store (row-contiguous)
      {
        const int row = tid >> 6, c4 = (tid & 63) * 4;
        float hv[4];
        #pragma unroll
        for (int e = 0; e < 4; ++e)
          hv[e] = s_lds[((c4 + e) >> 4) * 256 + row * 16 + ((c4 + e) & 15)];
        sta8(hx_ws + (size_t)(r0 + row) * HH + c4, pack4(hv[0], hv[1], hv[2], hv[3]));
        *(float4*)(out + (size_t)t * 65536 + (size_t)(r0 + row) * 256 + c4) =
            make_float4(hv[0], hv[1], hv[2], hv[3]);
        if (t == SEQ - 1)
          *(float4*)(out + (size_t)SEQ * 65536 + (size_t)(r0 + row) * 256 + c4) =
              make_float4(hv[0], hv[1], hv[2], hv[3]);
      }
    }
    gbar(flags, rel, wg, ++bexp);
  }
}

extern "C" void kernel_launch(void* const* d_in, const int* in_sizes, int n_in,
                              void* d_out, int out_size, void* d_ws, size_t ws_size,
                              hipStream_t stream) {
  const float* x   = (const float*)d_in[0];
  const float* Wq  = (const float*)d_in[1];
  const float* Wk  = (const float*)d_in[2];
  const float* Wv  = (const float*)d_in[3];
  const float* Wf  = (const float*)d_in[4];
  const float* bfv = (const float*)d_in[5];
  const float* Wi  = (const float*)d_in[6];
  const float* biv = (const float*)d_in[7];
  const float* Wgg = (const float*)d_in[8];
  const float* bgv = (const float*)d_in[9];
  const float* Wo  = (const float*)d_in[10];
  const float* bov = (const float*)d_in[11];
  float* out = (float*)d_out;
  char* wsb = (char*)d_ws;

  hipLaunchKernelGGL(qlstm_init_kernel, dim3(512), dim3(256), 0, stream,
                     Wq, Wk, Wv, Wf, Wi, Wgg, Wo, wsb);

  void* args[] = { (void*)&x, (void*)&bfv, (void*)&biv, (void*)&bgv, (void*)&bov,
                   (void*)&out, (void*)&wsb };
  hipLaunchCooperativeKernel((void*)qlstm_main_kernel, dim3(NWG), dim3(1024),
                             args, 0, stream);
}